// Round 10
// baseline (383.067 us; speedup 1.0000x reference)
//
#include <hip/hip_runtime.h>
#include <hip/hip_bf16.h>
#include <cstdint>
#include <cstddef>

#define S_LEN 4096
#define C_DIM 512
#define H_NUM 8
#define DH 64
#define MAXC 80
#define NSPLIT 64
#define DENSE_TASKS 16  // 2 dense rows * 8 heads

typedef short short8 __attribute__((ext_vector_type(8)));
typedef float f32x4 __attribute__((ext_vector_type(4)));

// ---------------------------------------------------------------------------
// bf16 helpers (manual RNE)
// ---------------------------------------------------------------------------
__device__ __forceinline__ unsigned short f2bf(float f) {
  union { float f; uint32_t u; } c; c.f = f;
  uint32_t u = c.u;
  uint32_t r = (u + 0x7fffu + ((u >> 16) & 1u)) >> 16;
  return (unsigned short)r;
}
__device__ __forceinline__ float bf2f(unsigned short h) {
  union { uint32_t u; float f; } c; c.u = ((uint32_t)h) << 16;
  return c.f;
}

__device__ __forceinline__ void split4(float4 v, ushort4& h, ushort4& l) {
  h.x = f2bf(v.x); l.x = f2bf(v.x - bf2f(h.x));
  h.y = f2bf(v.y); l.y = f2bf(v.y - bf2f(h.y));
  h.z = f2bf(v.z); l.z = f2bf(v.z - bf2f(h.z));
  h.w = f2bf(v.w); l.w = f2bf(v.w - bf2f(h.w));
}

__global__ __launch_bounds__(256) void split_bf16(const float* __restrict__ src,
                                                  unsigned short* __restrict__ hi,
                                                  unsigned short* __restrict__ lo,
                                                  int n4) {
  int idx = blockIdx.x * 256 + threadIdx.x;
  if (idx >= n4) return;
  float4 v = ((const float4*)src)[idx];
  ushort4 h, l;
  split4(v, h, l);
  ((ushort4*)hi)[idx] = h;
  ((ushort4*)lo)[idx] = l;
}

// fused 4-weight split: blockIdx.y selects {Wq,Wk,Wv,Wo}
__global__ __launch_bounds__(256) void split_bf16_w4(
    const float* __restrict__ Wq, const float* __restrict__ Wk,
    const float* __restrict__ Wv, const float* __restrict__ Wo,
    unsigned short* __restrict__ W4h, unsigned short* __restrict__ W4l) {
  const int z = blockIdx.y;
  const float* src = (z == 0) ? Wq : (z == 1) ? Wk : (z == 2) ? Wv : Wo;
  const size_t NW4 = (size_t)C_DIM * C_DIM / 4;
  int idx = blockIdx.x * 256 + threadIdx.x;  // grid.x = NW4/256 exactly
  float4 v = ((const float4*)src)[idx];
  ushort4 h, l;
  split4(v, h, l);
  ((ushort4*)(W4h))[z * NW4 + idx] = h;
  ((ushort4*)(W4l))[z * NW4 + idx] = l;
}

// ---------------------------------------------------------------------------
// Split-bf16 MFMA TN GEMM (verified round 5/8: absmax 3.9e-3)
// ---------------------------------------------------------------------------
__device__ __forceinline__ void gemm_mfma_body(
    const unsigned short* __restrict__ Ah, const unsigned short* __restrict__ Al,
    const unsigned short* __restrict__ Bh, const unsigned short* __restrict__ Bl,
    const float* __restrict__ bias, float* __restrict__ C) {
  const int lane = threadIdx.x & 63;
  const int wave = threadIdx.x >> 6;
  const int m_base = blockIdx.y * 128 + (wave >> 1) * 64;
  const int n_base = blockIdx.x * 64 + (wave & 1) * 32;
  const int rfrag = lane & 15;
  const int koff = (lane >> 4) * 8;

  f32x4 acc[4][2];
#pragma unroll
  for (int mi = 0; mi < 4; ++mi)
#pragma unroll
    for (int ni = 0; ni < 2; ++ni) acc[mi][ni] = (f32x4){0.f, 0.f, 0.f, 0.f};

  for (int ks = 0; ks < C_DIM; ks += 32) {
    const int kb = ks + koff;
    short8 ah[4], al[4], bh[2], bl[2];
#pragma unroll
    for (int mi = 0; mi < 4; ++mi) {
      const size_t off = (size_t)(m_base + mi * 16 + rfrag) * C_DIM + kb;
      ah[mi] = *(const short8*)(Ah + off);
      al[mi] = *(const short8*)(Al + off);
    }
#pragma unroll
    for (int ni = 0; ni < 2; ++ni) {
      const size_t off = (size_t)(n_base + ni * 16 + rfrag) * C_DIM + kb;
      bh[ni] = *(const short8*)(Bh + off);
      bl[ni] = *(const short8*)(Bl + off);
    }
#pragma unroll
    for (int mi = 0; mi < 4; ++mi)
#pragma unroll
      for (int ni = 0; ni < 2; ++ni) {
        acc[mi][ni] = __builtin_amdgcn_mfma_f32_16x16x32_bf16(ah[mi], bh[ni], acc[mi][ni], 0, 0, 0);
        acc[mi][ni] = __builtin_amdgcn_mfma_f32_16x16x32_bf16(ah[mi], bl[ni], acc[mi][ni], 0, 0, 0);
        acc[mi][ni] = __builtin_amdgcn_mfma_f32_16x16x32_bf16(al[mi], bh[ni], acc[mi][ni], 0, 0, 0);
      }
  }

  const int col = lane & 15;
  const int r0 = (lane >> 4) * 4;
#pragma unroll
  for (int mi = 0; mi < 4; ++mi)
#pragma unroll
    for (int ni = 0; ni < 2; ++ni) {
      const float b = bias[n_base + ni * 16 + col];
#pragma unroll
      for (int r = 0; r < 4; ++r) {
        C[(size_t)(m_base + mi * 16 + r0 + r) * C_DIM + n_base + ni * 16 + col] =
            acc[mi][ni][r] + b;
      }
    }
}

__global__ __launch_bounds__(256) void qkv_gemm_mfma(
    const unsigned short* __restrict__ xh, const unsigned short* __restrict__ xl,
    const unsigned short* __restrict__ W4h, const unsigned short* __restrict__ W4l,
    const float* __restrict__ bq, const float* __restrict__ bk,
    const float* __restrict__ bv, float* __restrict__ Qbase) {
  const int z = blockIdx.z;
  const size_t NW = (size_t)C_DIM * C_DIM;
  const float* bias = (z == 0) ? bq : (z == 1) ? bk : bv;
  gemm_mfma_body(xh, xl, W4h + z * NW, W4l + z * NW, bias,
                 Qbase + z * (size_t)S_LEN * C_DIM);
}

__global__ __launch_bounds__(256) void o_gemm_mfma(
    const unsigned short* __restrict__ AOh, const unsigned short* __restrict__ AOl,
    const unsigned short* __restrict__ W4h, const unsigned short* __restrict__ W4l,
    const float* __restrict__ bo, float* __restrict__ out) {
  const size_t NW = (size_t)C_DIM * C_DIM;
  gemm_mfma_body(AOh, AOl, W4h + 3 * NW, W4l + 3 * NW, bo, out);
}

// ---------------------------------------------------------------------------
// Mask scan (runtime dtype probe; verified)
// ---------------------------------------------------------------------------
__global__ __launch_bounds__(256) void scan_mask(const uint32_t* __restrict__ mask32,
                                                 int* __restrict__ counts,
                                                 int* __restrict__ cols) {
  int i = blockIdx.x;
  int tid = threadIdx.x;
  if (i == 0 || i == S_LEN - 1) {
    if (tid == 0) counts[i] = 0;
    return;
  }
  __shared__ int cnt;
  __shared__ int list[MAXC];
  if (tid == 0) cnt = 0;
  __syncthreads();

  const bool is_b32 = (mask32[0] == 1u);  // else 0x01010101 (byte mask)
  if (is_b32) {
    const uint4* m4 = (const uint4*)(mask32 + (size_t)i * S_LEN);
#pragma unroll
    for (int q = 0; q < 4; ++q) {
      uint4 v = m4[tid * 4 + q];
      int base = tid * 16 + q * 4;
      if (v.x) { int p = atomicAdd(&cnt, 1); if (p < MAXC) list[p] = base + 0; }
      if (v.y) { int p = atomicAdd(&cnt, 1); if (p < MAXC) list[p] = base + 1; }
      if (v.z) { int p = atomicAdd(&cnt, 1); if (p < MAXC) list[p] = base + 2; }
      if (v.w) { int p = atomicAdd(&cnt, 1); if (p < MAXC) list[p] = base + 3; }
    }
  } else {
    const uint8_t* mrow = (const uint8_t*)mask32 + (size_t)i * S_LEN;
    uint4 mv = ((const uint4*)mrow)[tid];
    uint32_t w[4] = {mv.x, mv.y, mv.z, mv.w};
#pragma unroll
    for (int q = 0; q < 4; ++q)
#pragma unroll
      for (int b = 0; b < 4; ++b) {
        if ((w[q] >> (8 * b)) & 0xffu) {
          int p = atomicAdd(&cnt, 1);
          if (p < MAXC) list[p] = tid * 16 + q * 4 + b;
        }
      }
  }
  __syncthreads();
  int n = cnt < MAXC ? cnt : MAXC;
  if (tid == 0) counts[i] = n;
  for (int t = tid; t < n; t += 256) cols[(size_t)i * MAXC + t] = list[t];
}

// ---------------------------------------------------------------------------
// Sparse attention v3.
// Round-8 diagnosis: VGPR_Count=24 -> compiler serialized the 16 K-loads of
// each QK dot (one vmcnt(0) per load). Fix: (a) QK loads K-row halves into an
// explicit float4 kr[8] register array (8 loads in flight, 2 exposures/pass);
// (b) PV vectorized: lane = (g,t), each lane loads a float4 of V, 4 cols per
// round, 20 float4 loads total (vs 80 scalar), cross-group shfl_xor reduce.
// Target <= ~56 VGPR so occupancy stays at 32 waves/CU.
// ---------------------------------------------------------------------------
__global__ __launch_bounds__(256) void attn_sparse(
    const float* __restrict__ Q, const float* __restrict__ K,
    const float* __restrict__ V, const int* __restrict__ counts,
    const int* __restrict__ cols, float* __restrict__ AO) {
  int wid = threadIdx.x >> 6, lane = threadIdx.x & 63;
  int task = blockIdx.x * 4 + wid;
  int i = task >> 3, h = task & 7;
  if (i == 0 || i == S_LEN - 1) return;

  __shared__ float q_lds[4][DH];
  __shared__ float ps[4][MAXC];
  __shared__ int   cs[4][MAXC];

  q_lds[wid][lane] = Q[(size_t)i * C_DIM + h * DH + lane];
  asm volatile("s_waitcnt lgkmcnt(0)" ::: "memory");
  const float4* q4 = (const float4*)q_lds[wid];

  int n = counts[i];
  if (n < 1) {
    AO[(size_t)i * C_DIM + h * DH + lane] = 0.f;
    return;
  }
  const int* cl = cols + (size_t)i * MAXC;
  const bool a0 = lane < n;
  const bool a1 = 64 + lane < n;
  int c0 = a0 ? cl[lane] : 0;
  int c1 = a1 ? cl[64 + lane] : 0;

  // --- QK dot for c0: two half-row passes, 8 float4 loads in flight each ---
  float s0d = 0.f;
  {
    const float4* kp = (const float4*)(K + (size_t)c0 * C_DIM + h * DH);
    float4 kr[8];
#pragma unroll
    for (int dd = 0; dd < 8; ++dd) kr[dd] = kp[dd];
#pragma unroll
    for (int dd = 0; dd < 8; ++dd) {
      float4 qv = q4[dd];
      s0d += kr[dd].x * qv.x + kr[dd].y * qv.y + kr[dd].z * qv.z + kr[dd].w * qv.w;
    }
#pragma unroll
    for (int dd = 0; dd < 8; ++dd) kr[dd] = kp[8 + dd];
#pragma unroll
    for (int dd = 0; dd < 8; ++dd) {
      float4 qv = q4[8 + dd];
      s0d += kr[dd].x * qv.x + kr[dd].y * qv.y + kr[dd].z * qv.z + kr[dd].w * qv.w;
    }
  }
  // --- QK dot for c1 (wave-uniform skip when the whole second half is empty)
  float s1d = 0.f;
  if (n > 64) {
    const float4* kp = (const float4*)(K + (size_t)c1 * C_DIM + h * DH);
    float4 kr[8];
#pragma unroll
    for (int dd = 0; dd < 8; ++dd) kr[dd] = kp[dd];
#pragma unroll
    for (int dd = 0; dd < 8; ++dd) {
      float4 qv = q4[dd];
      s1d += kr[dd].x * qv.x + kr[dd].y * qv.y + kr[dd].z * qv.z + kr[dd].w * qv.w;
    }
#pragma unroll
    for (int dd = 0; dd < 8; ++dd) kr[dd] = kp[8 + dd];
#pragma unroll
    for (int dd = 0; dd < 8; ++dd) {
      float4 qv = q4[8 + dd];
      s1d += kr[dd].x * qv.x + kr[dd].y * qv.y + kr[dd].z * qv.z + kr[dd].w * qv.w;
    }
  }
  float s0 = a0 ? s0d * 0.125f : -INFINITY;
  float s1 = a1 ? s1d * 0.125f : -INFINITY;

  float mx = fmaxf(s0, s1);
#pragma unroll
  for (int off = 32; off; off >>= 1) mx = fmaxf(mx, __shfl_xor(mx, off));
  float p0 = __expf(s0 - mx);  // 0 for inactive lanes
  float p1 = __expf(s1 - mx);
  float l = p0 + p1;
#pragma unroll
  for (int off = 32; off; off >>= 1) l += __shfl_xor(l, off);
  float rl = 1.0f / l;

  // stage pre-normalized p and col into LDS; pad slots are {0, 0}
  ps[wid][lane] = p0 * rl;
  cs[wid][lane] = c0;
  if (lane < MAXC - 64) {
    ps[wid][64 + lane] = a1 ? p1 * rl : 0.f;
    cs[wid][64 + lane] = a1 ? c1 : 0;
  }
  asm volatile("s_waitcnt lgkmcnt(0)" ::: "memory");

  // --- PV: lane (g,t); 4 cols per round via float4 V loads, 4 rounds/iter ---
  const int g = lane >> 4, t = lane & 15;
  float4 acc = {0.f, 0.f, 0.f, 0.f};
  const float* Vb = V + h * DH + t * 4;
  const int npad16 = (n + 15) & ~15;  // <= MAXC = 80
  for (int j = 0; j < npad16; j += 16) {
    float p[4];
    float4 v[4];
#pragma unroll
    for (int u = 0; u < 4; ++u) {
      int slot = j + u * 4 + g;
      int c = cs[wid][slot];
      p[u] = ps[wid][slot];
      v[u] = *(const float4*)(Vb + (size_t)c * C_DIM);
    }
#pragma unroll
    for (int u = 0; u < 4; ++u) {
      acc.x = fmaf(p[u], v[u].x, acc.x);
      acc.y = fmaf(p[u], v[u].y, acc.y);
      acc.z = fmaf(p[u], v[u].z, acc.z);
      acc.w = fmaf(p[u], v[u].w, acc.w);
    }
  }
  // reduce partial sums across the 4 lane-groups
  acc.x += __shfl_xor(acc.x, 16); acc.x += __shfl_xor(acc.x, 32);
  acc.y += __shfl_xor(acc.y, 16); acc.y += __shfl_xor(acc.y, 32);
  acc.z += __shfl_xor(acc.z, 16); acc.z += __shfl_xor(acc.z, 32);
  acc.w += __shfl_xor(acc.w, 16); acc.w += __shfl_xor(acc.w, 32);
  if (g == 0) {
    *(float4*)(AO + (size_t)i * C_DIM + h * DH + t * 4) = acc;
  }
}

// ---------------------------------------------------------------------------
// Dense rows (0, S-1): NSPLIT=64, one 64-col chunk per wave (verified r8)
// ---------------------------------------------------------------------------
__global__ __launch_bounds__(256) void attn_dense(const float* __restrict__ Q,
                                                  const float* __restrict__ K,
                                                  const float* __restrict__ V,
                                                  float* __restrict__ part) {
  int wid = threadIdx.x >> 6, lane = threadIdx.x & 63;
  int gid = blockIdx.x * 4 + wid;  // 0..1023
  int task = gid >> 6;             // 0..15
  int split = gid & 63;
  int i = (task >> 3) ? (S_LEN - 1) : 0;
  int h = task & 7;

  __shared__ float q_lds[4][DH];
  __shared__ float pd[4][64];
  q_lds[wid][lane] = Q[(size_t)i * C_DIM + h * DH + lane];
  asm volatile("s_waitcnt lgkmcnt(0)" ::: "memory");
  const float4* q4 = (const float4*)q_lds[wid];

  const int c = split * 64 + lane;
  const float4* kp = (const float4*)(K + (size_t)c * C_DIM + h * DH);
  float s = 0.f;
#pragma unroll
  for (int dd = 0; dd < 16; ++dd) {
    float4 kv = kp[dd], qv = q4[dd];
    s += qv.x * kv.x + qv.y * kv.y + qv.z * kv.z + qv.w * kv.w;
  }
  s *= 0.125f;
  float m = s;
#pragma unroll
  for (int off = 32; off; off >>= 1) m = fmaxf(m, __shfl_xor(m, off));
  float p = __expf(s - m);
  float l = p;
#pragma unroll
  for (int off = 32; off; off >>= 1) l += __shfl_xor(l, off);

  pd[wid][lane] = p;
  asm volatile("s_waitcnt lgkmcnt(0)" ::: "memory");

  float acc = 0.f;
  const float* Vb = V + (size_t)(split * 64) * C_DIM + h * DH + lane;
  for (int j0 = 0; j0 < 64; j0 += 8) {
    float pj[8], vv[8];
#pragma unroll
    for (int u = 0; u < 8; ++u) {
      pj[u] = pd[wid][j0 + u];
      vv[u] = Vb[(size_t)(j0 + u) * C_DIM];
    }
#pragma unroll
    for (int u = 0; u < 8; ++u) acc = fmaf(pj[u], vv[u], acc);
  }
  float* pt = part + (size_t)(task * NSPLIT + split) * 68;
  pt[lane] = acc;
  if (lane == 0) {
    pt[64] = m;
    pt[65] = l;
  }
}

__global__ __launch_bounds__(64) void attn_combine(const float* __restrict__ part,
                                                   float* __restrict__ AO) {
  int task = blockIdx.x;  // 0..15
  int lane = threadIdx.x;
  float m = -INFINITY;
  for (int sp = 0; sp < NSPLIT; ++sp)
    m = fmaxf(m, part[(size_t)(task * NSPLIT + sp) * 68 + 64]);
  float l = 0.f, acc = 0.f;
  for (int sp = 0; sp < NSPLIT; ++sp) {
    const float* pt = part + (size_t)(task * NSPLIT + sp) * 68;
    float w = __expf(pt[64] - m);
    l += w * pt[65];
    acc += w * pt[lane];
  }
  int i = (task >> 3) ? (S_LEN - 1) : 0;
  int h = task & 7;
  AO[(size_t)i * C_DIM + h * DH + lane] = acc / l;
}

// ---------------------------------------------------------------------------
extern "C" void kernel_launch(void* const* d_in, const int* in_sizes, int n_in,
                              void* d_out, int out_size, void* d_ws,
                              size_t ws_size, hipStream_t stream) {
  const float* x = (const float*)d_in[0];
  const uint32_t* mask = (const uint32_t*)d_in[1];
  const float* Wq = (const float*)d_in[2];
  const float* bq = (const float*)d_in[3];
  const float* Wk = (const float*)d_in[4];
  const float* bk = (const float*)d_in[5];
  const float* Wv = (const float*)d_in[6];
  const float* bv = (const float*)d_in[7];
  const float* Wo = (const float*)d_in[8];
  const float* bo = (const float*)d_in[9];
  float* out = (float*)d_out;

  const size_t NELT = (size_t)S_LEN * C_DIM;  // 2,097,152
  const size_t NW = (size_t)C_DIM * C_DIM;    // 262,144

  float* Q = (float*)d_ws;
  float* Kb = Q + NELT;
  float* Vb = Kb + NELT;
  float* AO = Vb + NELT;
  int* counts = (int*)(AO + NELT);
  int* colsl = counts + S_LEN;
  float* part = (float*)(colsl + (size_t)S_LEN * MAXC);
  unsigned short* xh = (unsigned short*)(part + (size_t)DENSE_TASKS * NSPLIT * 68);
  unsigned short* xl = xh + NELT;
  unsigned short* AOh = xl + NELT;
  unsigned short* AOl = AOh + NELT;
  unsigned short* W4h = AOl + NELT;  // 4 * NW (q,k,v,o)
  unsigned short* W4l = W4h + 4 * NW;

  scan_mask<<<S_LEN, 256, 0, stream>>>(mask, counts, colsl);

  split_bf16<<<(NELT / 4 + 255) / 256, 256, 0, stream>>>(x, xh, xl, NELT / 4);
  split_bf16_w4<<<dim3(NW / 4 / 256, 4), 256, 0, stream>>>(Wq, Wk, Wv, Wo, W4h, W4l);
  qkv_gemm_mfma<<<dim3(C_DIM / 64, S_LEN / 128, 3), 256, 0, stream>>>(
      xh, xl, W4h, W4l, bq, bk, bv, Q);

  attn_sparse<<<(S_LEN * H_NUM) / 4, 256, 0, stream>>>(Q, Kb, Vb, counts, colsl, AO);
  attn_dense<<<(DENSE_TASKS * NSPLIT) / 4, 256, 0, stream>>>(Q, Kb, Vb, part);
  attn_combine<<<DENSE_TASKS, 64, 0, stream>>>(part, AO);

  split_bf16<<<(NELT / 4 + 255) / 256, 256, 0, stream>>>(AO, AOh, AOl, NELT / 4);
  o_gemm_mfma<<<dim3(C_DIM / 64, S_LEN / 128, 1), 256, 0, stream>>>(
      AOh, AOl, W4h, W4l, bo, out);
}

// Round 11
// 336.503 us; speedup vs baseline: 1.1384x; 1.1384x over previous
//
#include <hip/hip_runtime.h>
#include <hip/hip_bf16.h>
#include <cstdint>
#include <cstddef>

#define S_LEN 4096
#define C_DIM 512
#define H_NUM 8
#define DH 64
#define MAXC 80
#define NSPLIT 64
#define DENSE_TASKS 16  // 2 dense rows * 8 heads

typedef short short8 __attribute__((ext_vector_type(8)));
typedef float f32x4 __attribute__((ext_vector_type(4)));

// ---------------------------------------------------------------------------
// bf16 helpers (manual RNE)
// ---------------------------------------------------------------------------
__device__ __forceinline__ unsigned short f2bf(float f) {
  union { float f; uint32_t u; } c; c.f = f;
  uint32_t u = c.u;
  uint32_t r = (u + 0x7fffu + ((u >> 16) & 1u)) >> 16;
  return (unsigned short)r;
}
__device__ __forceinline__ float bf2f(unsigned short h) {
  union { uint32_t u; float f; } c; c.u = ((uint32_t)h) << 16;
  return c.f;
}

__device__ __forceinline__ void split4(float4 v, ushort4& h, ushort4& l) {
  h.x = f2bf(v.x); l.x = f2bf(v.x - bf2f(h.x));
  h.y = f2bf(v.y); l.y = f2bf(v.y - bf2f(h.y));
  h.z = f2bf(v.z); l.z = f2bf(v.z - bf2f(h.z));
  h.w = f2bf(v.w); l.w = f2bf(v.w - bf2f(h.w));
}

__global__ __launch_bounds__(256) void split_bf16(const float* __restrict__ src,
                                                  unsigned short* __restrict__ hi,
                                                  unsigned short* __restrict__ lo,
                                                  int n4) {
  int idx = blockIdx.x * 256 + threadIdx.x;
  if (idx >= n4) return;
  float4 v = ((const float4*)src)[idx];
  ushort4 h, l;
  split4(v, h, l);
  ((ushort4*)hi)[idx] = h;
  ((ushort4*)lo)[idx] = l;
}

// fused 4-weight split: blockIdx.y selects {Wq,Wk,Wv,Wo}
__global__ __launch_bounds__(256) void split_bf16_w4(
    const float* __restrict__ Wq, const float* __restrict__ Wk,
    const float* __restrict__ Wv, const float* __restrict__ Wo,
    unsigned short* __restrict__ W4h, unsigned short* __restrict__ W4l) {
  const int z = blockIdx.y;
  const float* src = (z == 0) ? Wq : (z == 1) ? Wk : (z == 2) ? Wv : Wo;
  const size_t NW4 = (size_t)C_DIM * C_DIM / 4;
  int idx = blockIdx.x * 256 + threadIdx.x;  // grid.x = NW4/256 exactly
  float4 v = ((const float4*)src)[idx];
  ushort4 h, l;
  split4(v, h, l);
  ((ushort4*)(W4h))[z * NW4 + idx] = h;
  ((ushort4*)(W4l))[z * NW4 + idx] = l;
}

// ---------------------------------------------------------------------------
// Split-bf16 MFMA TN GEMM (verified rounds 5/8/10: absmax 3.9e-3)
// ---------------------------------------------------------------------------
__device__ __forceinline__ void gemm_mfma_body(
    const unsigned short* __restrict__ Ah, const unsigned short* __restrict__ Al,
    const unsigned short* __restrict__ Bh, const unsigned short* __restrict__ Bl,
    const float* __restrict__ bias, float* __restrict__ C) {
  const int lane = threadIdx.x & 63;
  const int wave = threadIdx.x >> 6;
  const int m_base = blockIdx.y * 128 + (wave >> 1) * 64;
  const int n_base = blockIdx.x * 64 + (wave & 1) * 32;
  const int rfrag = lane & 15;
  const int koff = (lane >> 4) * 8;

  f32x4 acc[4][2];
#pragma unroll
  for (int mi = 0; mi < 4; ++mi)
#pragma unroll
    for (int ni = 0; ni < 2; ++ni) acc[mi][ni] = (f32x4){0.f, 0.f, 0.f, 0.f};

  for (int ks = 0; ks < C_DIM; ks += 32) {
    const int kb = ks + koff;
    short8 ah[4], al[4], bh[2], bl[2];
#pragma unroll
    for (int mi = 0; mi < 4; ++mi) {
      const size_t off = (size_t)(m_base + mi * 16 + rfrag) * C_DIM + kb;
      ah[mi] = *(const short8*)(Ah + off);
      al[mi] = *(const short8*)(Al + off);
    }
#pragma unroll
    for (int ni = 0; ni < 2; ++ni) {
      const size_t off = (size_t)(n_base + ni * 16 + rfrag) * C_DIM + kb;
      bh[ni] = *(const short8*)(Bh + off);
      bl[ni] = *(const short8*)(Bl + off);
    }
#pragma unroll
    for (int mi = 0; mi < 4; ++mi)
#pragma unroll
      for (int ni = 0; ni < 2; ++ni) {
        acc[mi][ni] = __builtin_amdgcn_mfma_f32_16x16x32_bf16(ah[mi], bh[ni], acc[mi][ni], 0, 0, 0);
        acc[mi][ni] = __builtin_amdgcn_mfma_f32_16x16x32_bf16(ah[mi], bl[ni], acc[mi][ni], 0, 0, 0);
        acc[mi][ni] = __builtin_amdgcn_mfma_f32_16x16x32_bf16(al[mi], bh[ni], acc[mi][ni], 0, 0, 0);
      }
  }

  const int col = lane & 15;
  const int r0 = (lane >> 4) * 4;
#pragma unroll
  for (int mi = 0; mi < 4; ++mi)
#pragma unroll
    for (int ni = 0; ni < 2; ++ni) {
      const float b = bias[n_base + ni * 16 + col];
#pragma unroll
      for (int r = 0; r < 4; ++r) {
        C[(size_t)(m_base + mi * 16 + r0 + r) * C_DIM + n_base + ni * 16 + col] =
            acc[mi][ni][r] + b;
      }
    }
}

__global__ __launch_bounds__(256) void qkv_gemm_mfma(
    const unsigned short* __restrict__ xh, const unsigned short* __restrict__ xl,
    const unsigned short* __restrict__ W4h, const unsigned short* __restrict__ W4l,
    const float* __restrict__ bq, const float* __restrict__ bk,
    const float* __restrict__ bv, float* __restrict__ Qbase) {
  const int z = blockIdx.z;
  const size_t NW = (size_t)C_DIM * C_DIM;
  const float* bias = (z == 0) ? bq : (z == 1) ? bk : bv;
  gemm_mfma_body(xh, xl, W4h + z * NW, W4l + z * NW, bias,
                 Qbase + z * (size_t)S_LEN * C_DIM);
}

__global__ __launch_bounds__(256) void o_gemm_mfma(
    const unsigned short* __restrict__ AOh, const unsigned short* __restrict__ AOl,
    const unsigned short* __restrict__ W4h, const unsigned short* __restrict__ W4l,
    const float* __restrict__ bo, float* __restrict__ out) {
  const size_t NW = (size_t)C_DIM * C_DIM;
  gemm_mfma_body(AOh, AOl, W4h + 3 * NW, W4l + 3 * NW, bo, out);
}

// ---------------------------------------------------------------------------
// Mask scan (runtime dtype probe; verified)
// ---------------------------------------------------------------------------
__global__ __launch_bounds__(256) void scan_mask(const uint32_t* __restrict__ mask32,
                                                 int* __restrict__ counts,
                                                 int* __restrict__ cols) {
  int i = blockIdx.x;
  int tid = threadIdx.x;
  if (i == 0 || i == S_LEN - 1) {
    if (tid == 0) counts[i] = 0;
    return;
  }
  __shared__ int cnt;
  __shared__ int list[MAXC];
  if (tid == 0) cnt = 0;
  __syncthreads();

  const bool is_b32 = (mask32[0] == 1u);  // else 0x01010101 (byte mask)
  if (is_b32) {
    const uint4* m4 = (const uint4*)(mask32 + (size_t)i * S_LEN);
#pragma unroll
    for (int q = 0; q < 4; ++q) {
      uint4 v = m4[tid * 4 + q];
      int base = tid * 16 + q * 4;
      if (v.x) { int p = atomicAdd(&cnt, 1); if (p < MAXC) list[p] = base + 0; }
      if (v.y) { int p = atomicAdd(&cnt, 1); if (p < MAXC) list[p] = base + 1; }
      if (v.z) { int p = atomicAdd(&cnt, 1); if (p < MAXC) list[p] = base + 2; }
      if (v.w) { int p = atomicAdd(&cnt, 1); if (p < MAXC) list[p] = base + 3; }
    }
  } else {
    const uint8_t* mrow = (const uint8_t*)mask32 + (size_t)i * S_LEN;
    uint4 mv = ((const uint4*)mrow)[tid];
    uint32_t w[4] = {mv.x, mv.y, mv.z, mv.w};
#pragma unroll
    for (int q = 0; q < 4; ++q)
#pragma unroll
      for (int b = 0; b < 4; ++b) {
        if ((w[q] >> (8 * b)) & 0xffu) {
          int p = atomicAdd(&cnt, 1);
          if (p < MAXC) list[p] = tid * 16 + q * 4 + b;
        }
      }
  }
  __syncthreads();
  int n = cnt < MAXC ? cnt : MAXC;
  if (tid == 0) counts[i] = n;
  for (int t = tid; t < n; t += 256) cols[(size_t)i * MAXC + t] = list[t];
}

// ---------------------------------------------------------------------------
// Sparse attention v4.
// Round-10 lesson: 8-deep reg batching -> 120 VGPR -> occupancy 22% (cliff).
// v4: (a) coalesced QK: lane=(q,c), 4 lanes/col, each lane loads its own
//     64B line (4 float4, fully consumed) -> per-task K traffic = exact bytes;
//     scores via shfl_xor(16,32) -> LDS. Only kr[4] = 16 VGPR.
// (b) XCD-chunked swizzle: each XCD gets a contiguous 512-row range; its
//     window working set (~2.7 MB K+V slices) fits the 4 MB private L2.
// (c) __launch_bounds__(256,8) pins 8 waves/EU (VGPR <= 64).
// (d) PV = v2 proven form: coalesced scalar V loads, 8-wide batches.
// ---------------------------------------------------------------------------
__global__ __launch_bounds__(256, 8) void attn_sparse(
    const float* __restrict__ Q, const float* __restrict__ K,
    const float* __restrict__ V, const int* __restrict__ counts,
    const int* __restrict__ cols, float* __restrict__ AO) {
  // XCD-chunked bijective swizzle (gridDim.x = 8192, divisible by 8)
  int bid = blockIdx.x;
  int bid2 = (bid & 7) * (int)(gridDim.x >> 3) + (bid >> 3);
  int wid = threadIdx.x >> 6, lane = threadIdx.x & 63;
  int task = bid2 * 4 + wid;
  int i = task >> 3, h = task & 7;
  if (i == 0 || i == S_LEN - 1) return;

  __shared__ float q_lds[4][DH];
  __shared__ float sc[4][MAXC];
  __shared__ float ps[4][MAXC];
  __shared__ int   cs[4][MAXC];

  int n = counts[i];
  q_lds[wid][lane] = Q[(size_t)i * C_DIM + h * DH + lane];
  const int* cl = cols + (size_t)i * MAXC;
  cs[wid][lane] = (lane < n) ? cl[lane] : 0;
  if (lane < MAXC - 64) cs[wid][64 + lane] = (64 + lane < n) ? cl[64 + lane] : 0;
  asm volatile("s_waitcnt lgkmcnt(0)" ::: "memory");

  if (n < 1) {  // defensive; never true for interior rows
    AO[(size_t)i * C_DIM + h * DH + lane] = 0.f;
    return;
  }

  // --- QK: 4 lanes per column; lane (q,c) loads bytes [q*64, q*64+64) of
  //     col c's head-slice (one cache line, fully consumed). ---
  const int qq = lane >> 4, c = lane & 15;
  const float* qrow = q_lds[wid] + qq * 16;
  const int nchunk = (n + 15) >> 4;  // wave-uniform
  for (int ch = 0; ch < nchunk; ++ch) {
    int col = cs[wid][ch * 16 + c];
    const float4* kp = (const float4*)(K + (size_t)col * C_DIM + h * DH + qq * 16);
    float4 kr[4];
#pragma unroll
    for (int dd = 0; dd < 4; ++dd) kr[dd] = kp[dd];
    float s = 0.f;
#pragma unroll
    for (int dd = 0; dd < 4; ++dd) {
      float4 qv = *(const float4*)(qrow + dd * 4);
      s += kr[dd].x * qv.x + kr[dd].y * qv.y + kr[dd].z * qv.z + kr[dd].w * qv.w;
    }
    s += __shfl_xor(s, 16);
    s += __shfl_xor(s, 32);
    if (qq == 0) sc[wid][ch * 16 + c] = s * 0.125f;
  }
  asm volatile("s_waitcnt lgkmcnt(0)" ::: "memory");

  // --- softmax over the n scores (pad slots masked to -inf) ---
  float s0 = (lane < n) ? sc[wid][lane] : -INFINITY;
  float s1 = (64 + lane < n) ? sc[wid][64 + lane] : -INFINITY;
  float mx = fmaxf(s0, s1);
#pragma unroll
  for (int off = 32; off; off >>= 1) mx = fmaxf(mx, __shfl_xor(mx, off));
  float p0 = __expf(s0 - mx);  // 0 for masked lanes
  float p1 = __expf(s1 - mx);
  float l = p0 + p1;
#pragma unroll
  for (int off = 32; off; off >>= 1) l += __shfl_xor(l, off);
  float rl = 1.0f / l;

  ps[wid][lane] = p0 * rl;                       // pad slots -> 0
  if (lane < MAXC - 64) ps[wid][64 + lane] = p1 * rl;
  asm volatile("s_waitcnt lgkmcnt(0)" ::: "memory");

  // --- PV: lane = d; coalesced scalar V loads, 8 independent per batch ---
  float acc = 0.f;
  const float* Vh = V + h * DH + lane;
  const int npad = (n + 7) & ~7;  // <= MAXC, pad entries {p=0, col=0}
  for (int j0 = 0; j0 < npad; j0 += 8) {
    float pj[8], vv[8];
#pragma unroll
    for (int u = 0; u < 8; ++u) {
      pj[u] = ps[wid][j0 + u];
      vv[u] = Vh[(size_t)cs[wid][j0 + u] * C_DIM];
    }
#pragma unroll
    for (int u = 0; u < 8; ++u) acc = fmaf(pj[u], vv[u], acc);
  }
  AO[(size_t)i * C_DIM + h * DH + lane] = acc;
}

// ---------------------------------------------------------------------------
// Dense rows (0, S-1): NSPLIT=64, one 64-col chunk per wave (verified r8)
// ---------------------------------------------------------------------------
__global__ __launch_bounds__(256) void attn_dense(const float* __restrict__ Q,
                                                  const float* __restrict__ K,
                                                  const float* __restrict__ V,
                                                  float* __restrict__ part) {
  int wid = threadIdx.x >> 6, lane = threadIdx.x & 63;
  int gid = blockIdx.x * 4 + wid;  // 0..1023
  int task = gid >> 6;             // 0..15
  int split = gid & 63;
  int i = (task >> 3) ? (S_LEN - 1) : 0;
  int h = task & 7;

  __shared__ float q_lds[4][DH];
  __shared__ float pd[4][64];
  q_lds[wid][lane] = Q[(size_t)i * C_DIM + h * DH + lane];
  asm volatile("s_waitcnt lgkmcnt(0)" ::: "memory");
  const float4* q4 = (const float4*)q_lds[wid];

  const int c = split * 64 + lane;
  const float4* kp = (const float4*)(K + (size_t)c * C_DIM + h * DH);
  float s = 0.f;
#pragma unroll
  for (int dd = 0; dd < 16; ++dd) {
    float4 kv = kp[dd], qv = q4[dd];
    s += qv.x * kv.x + qv.y * kv.y + qv.z * kv.z + qv.w * kv.w;
  }
  s *= 0.125f;
  float m = s;
#pragma unroll
  for (int off = 32; off; off >>= 1) m = fmaxf(m, __shfl_xor(m, off));
  float p = __expf(s - m);
  float l = p;
#pragma unroll
  for (int off = 32; off; off >>= 1) l += __shfl_xor(l, off);

  pd[wid][lane] = p;
  asm volatile("s_waitcnt lgkmcnt(0)" ::: "memory");

  float acc = 0.f;
  const float* Vb = V + (size_t)(split * 64) * C_DIM + h * DH + lane;
  for (int j0 = 0; j0 < 64; j0 += 8) {
    float pj[8], vv[8];
#pragma unroll
    for (int u = 0; u < 8; ++u) {
      pj[u] = pd[wid][j0 + u];
      vv[u] = Vb[(size_t)(j0 + u) * C_DIM];
    }
#pragma unroll
    for (int u = 0; u < 8; ++u) acc = fmaf(pj[u], vv[u], acc);
  }
  float* pt = part + (size_t)(task * NSPLIT + split) * 68;
  pt[lane] = acc;
  if (lane == 0) {
    pt[64] = m;
    pt[65] = l;
  }
}

__global__ __launch_bounds__(64) void attn_combine(const float* __restrict__ part,
                                                   float* __restrict__ AO) {
  int task = blockIdx.x;  // 0..15
  int lane = threadIdx.x;
  float m = -INFINITY;
  for (int sp = 0; sp < NSPLIT; ++sp)
    m = fmaxf(m, part[(size_t)(task * NSPLIT + sp) * 68 + 64]);
  float l = 0.f, acc = 0.f;
  for (int sp = 0; sp < NSPLIT; ++sp) {
    const float* pt = part + (size_t)(task * NSPLIT + sp) * 68;
    float w = __expf(pt[64] - m);
    l += w * pt[65];
    acc += w * pt[lane];
  }
  int i = (task >> 3) ? (S_LEN - 1) : 0;
  int h = task & 7;
  AO[(size_t)i * C_DIM + h * DH + lane] = acc / l;
}

// ---------------------------------------------------------------------------
extern "C" void kernel_launch(void* const* d_in, const int* in_sizes, int n_in,
                              void* d_out, int out_size, void* d_ws,
                              size_t ws_size, hipStream_t stream) {
  const float* x = (const float*)d_in[0];
  const uint32_t* mask = (const uint32_t*)d_in[1];
  const float* Wq = (const float*)d_in[2];
  const float* bq = (const float*)d_in[3];
  const float* Wk = (const float*)d_in[4];
  const float* bk = (const float*)d_in[5];
  const float* Wv = (const float*)d_in[6];
  const float* bv = (const float*)d_in[7];
  const float* Wo = (const float*)d_in[8];
  const float* bo = (const float*)d_in[9];
  float* out = (float*)d_out;

  const size_t NELT = (size_t)S_LEN * C_DIM;  // 2,097,152
  const size_t NW = (size_t)C_DIM * C_DIM;    // 262,144

  float* Q = (float*)d_ws;
  float* Kb = Q + NELT;
  float* Vb = Kb + NELT;
  float* AO = Vb + NELT;
  int* counts = (int*)(AO + NELT);
  int* colsl = counts + S_LEN;
  float* part = (float*)(colsl + (size_t)S_LEN * MAXC);
  unsigned short* xh = (unsigned short*)(part + (size_t)DENSE_TASKS * NSPLIT * 68);
  unsigned short* xl = xh + NELT;
  unsigned short* AOh = xl + NELT;
  unsigned short* AOl = AOh + NELT;
  unsigned short* W4h = AOl + NELT;  // 4 * NW (q,k,v,o)
  unsigned short* W4l = W4h + 4 * NW;

  scan_mask<<<S_LEN, 256, 0, stream>>>(mask, counts, colsl);

  split_bf16<<<(NELT / 4 + 255) / 256, 256, 0, stream>>>(x, xh, xl, NELT / 4);
  split_bf16_w4<<<dim3(NW / 4 / 256, 4), 256, 0, stream>>>(Wq, Wk, Wv, Wo, W4h, W4l);
  qkv_gemm_mfma<<<dim3(C_DIM / 64, S_LEN / 128, 3), 256, 0, stream>>>(
      xh, xl, W4h, W4l, bq, bk, bv, Q);

  attn_sparse<<<(S_LEN * H_NUM) / 4, 256, 0, stream>>>(Q, Kb, Vb, counts, colsl, AO);
  attn_dense<<<(DENSE_TASKS * NSPLIT) / 4, 256, 0, stream>>>(Q, Kb, Vb, part);
  attn_combine<<<DENSE_TASKS, 64, 0, stream>>>(part, AO);

  split_bf16<<<(NELT / 4 + 255) / 256, 256, 0, stream>>>(AO, AOh, AOl, NELT / 4);
  o_gemm_mfma<<<dim3(C_DIM / 64, S_LEN / 128, 1), 256, 0, stream>>>(
      AOh, AOl, W4h, W4l, bo, out);
}

// Round 15
// 312.791 us; speedup vs baseline: 1.2247x; 1.0758x over previous
//
#include <hip/hip_runtime.h>
#include <hip/hip_bf16.h>
#include <cstdint>
#include <cstddef>

#define S_LEN 4096
#define C_DIM 512
#define H_NUM 8
#define DH 64
#define MAXC 80
#define NSPLIT 64
#define DENSE_TASKS 16  // 2 dense rows * 8 heads

typedef short short8 __attribute__((ext_vector_type(8)));
typedef float f32x4 __attribute__((ext_vector_type(4)));

// ---------------------------------------------------------------------------
// bf16 helpers (manual RNE)
// ---------------------------------------------------------------------------
__device__ __forceinline__ unsigned short f2bf(float f) {
  union { float f; uint32_t u; } c; c.f = f;
  uint32_t u = c.u;
  uint32_t r = (u + 0x7fffu + ((u >> 16) & 1u)) >> 16;
  return (unsigned short)r;
}
__device__ __forceinline__ float bf2f(unsigned short h) {
  union { uint32_t u; float f; } c; c.u = ((uint32_t)h) << 16;
  return c.f;
}

__device__ __forceinline__ void split4(float4 v, ushort4& h, ushort4& l) {
  h.x = f2bf(v.x); l.x = f2bf(v.x - bf2f(h.x));
  h.y = f2bf(v.y); l.y = f2bf(v.y - bf2f(h.y));
  h.z = f2bf(v.z); l.z = f2bf(v.z - bf2f(h.z));
  h.w = f2bf(v.w); l.w = f2bf(v.w - bf2f(h.w));
}

__global__ __launch_bounds__(256) void split_bf16(const float* __restrict__ src,
                                                  unsigned short* __restrict__ hi,
                                                  unsigned short* __restrict__ lo,
                                                  int n4) {
  int idx = blockIdx.x * 256 + threadIdx.x;
  if (idx >= n4) return;
  float4 v = ((const float4*)src)[idx];
  ushort4 h, l;
  split4(v, h, l);
  ((ushort4*)hi)[idx] = h;
  ((ushort4*)lo)[idx] = l;
}

// fused 4-weight split: blockIdx.y selects {Wq,Wk,Wv,Wo}
__global__ __launch_bounds__(256) void split_bf16_w4(
    const float* __restrict__ Wq, const float* __restrict__ Wk,
    const float* __restrict__ Wv, const float* __restrict__ Wo,
    unsigned short* __restrict__ W4h, unsigned short* __restrict__ W4l) {
  const int z = blockIdx.y;
  const float* src = (z == 0) ? Wq : (z == 1) ? Wk : (z == 2) ? Wv : Wo;
  const size_t NW4 = (size_t)C_DIM * C_DIM / 4;
  int idx = blockIdx.x * 256 + threadIdx.x;  // grid.x = NW4/256 exactly
  float4 v = ((const float4*)src)[idx];
  ushort4 h, l;
  split4(v, h, l);
  ((ushort4*)(W4h))[z * NW4 + idx] = h;
  ((ushort4*)(W4l))[z * NW4 + idx] = l;
}

// ---------------------------------------------------------------------------
// Split-bf16 MFMA TN GEMM (verified rounds 5/8/10/11: absmax 3.9e-3)
// ---------------------------------------------------------------------------
__device__ __forceinline__ void gemm_mfma_body(
    const unsigned short* __restrict__ Ah, const unsigned short* __restrict__ Al,
    const unsigned short* __restrict__ Bh, const unsigned short* __restrict__ Bl,
    const float* __restrict__ bias, float* __restrict__ C) {
  const int lane = threadIdx.x & 63;
  const int wave = threadIdx.x >> 6;
  const int m_base = blockIdx.y * 128 + (wave >> 1) * 64;
  const int n_base = blockIdx.x * 64 + (wave & 1) * 32;
  const int rfrag = lane & 15;
  const int koff = (lane >> 4) * 8;

  f32x4 acc[4][2];
#pragma unroll
  for (int mi = 0; mi < 4; ++mi)
#pragma unroll
    for (int ni = 0; ni < 2; ++ni) acc[mi][ni] = (f32x4){0.f, 0.f, 0.f, 0.f};

  for (int ks = 0; ks < C_DIM; ks += 32) {
    const int kb = ks + koff;
    short8 ah[4], al[4], bh[2], bl[2];
#pragma unroll
    for (int mi = 0; mi < 4; ++mi) {
      const size_t off = (size_t)(m_base + mi * 16 + rfrag) * C_DIM + kb;
      ah[mi] = *(const short8*)(Ah + off);
      al[mi] = *(const short8*)(Al + off);
    }
#pragma unroll
    for (int ni = 0; ni < 2; ++ni) {
      const size_t off = (size_t)(n_base + ni * 16 + rfrag) * C_DIM + kb;
      bh[ni] = *(const short8*)(Bh + off);
      bl[ni] = *(const short8*)(Bl + off);
    }
#pragma unroll
    for (int mi = 0; mi < 4; ++mi)
#pragma unroll
      for (int ni = 0; ni < 2; ++ni) {
        acc[mi][ni] = __builtin_amdgcn_mfma_f32_16x16x32_bf16(ah[mi], bh[ni], acc[mi][ni], 0, 0, 0);
        acc[mi][ni] = __builtin_amdgcn_mfma_f32_16x16x32_bf16(ah[mi], bl[ni], acc[mi][ni], 0, 0, 0);
        acc[mi][ni] = __builtin_amdgcn_mfma_f32_16x16x32_bf16(al[mi], bh[ni], acc[mi][ni], 0, 0, 0);
      }
  }

  const int col = lane & 15;
  const int r0 = (lane >> 4) * 4;
#pragma unroll
  for (int mi = 0; mi < 4; ++mi)
#pragma unroll
    for (int ni = 0; ni < 2; ++ni) {
      const float b = bias[n_base + ni * 16 + col];
#pragma unroll
      for (int r = 0; r < 4; ++r) {
        C[(size_t)(m_base + mi * 16 + r0 + r) * C_DIM + n_base + ni * 16 + col] =
            acc[mi][ni][r] + b;
      }
    }
}

__global__ __launch_bounds__(256) void qkv_gemm_mfma(
    const unsigned short* __restrict__ xh, const unsigned short* __restrict__ xl,
    const unsigned short* __restrict__ W4h, const unsigned short* __restrict__ W4l,
    const float* __restrict__ bq, const float* __restrict__ bk,
    const float* __restrict__ bv, float* __restrict__ Qbase) {
  const int z = blockIdx.z;
  const size_t NW = (size_t)C_DIM * C_DIM;
  const float* bias = (z == 0) ? bq : (z == 1) ? bk : bv;
  gemm_mfma_body(xh, xl, W4h + z * NW, W4l + z * NW, bias,
                 Qbase + z * (size_t)S_LEN * C_DIM);
}

__global__ __launch_bounds__(256) void o_gemm_mfma(
    const unsigned short* __restrict__ AOh, const unsigned short* __restrict__ AOl,
    const unsigned short* __restrict__ W4h, const unsigned short* __restrict__ W4l,
    const float* __restrict__ bo, float* __restrict__ out) {
  const size_t NW = (size_t)C_DIM * C_DIM;
  gemm_mfma_body(AOh, AOl, W4h + 3 * NW, W4l + 3 * NW, bo, out);
}

// ---------------------------------------------------------------------------
// Mask scan (runtime dtype probe; verified)
// ---------------------------------------------------------------------------
__global__ __launch_bounds__(256) void scan_mask(const uint32_t* __restrict__ mask32,
                                                 int* __restrict__ counts,
                                                 int* __restrict__ cols) {
  int i = blockIdx.x;
  int tid = threadIdx.x;
  if (i == 0 || i == S_LEN - 1) {
    if (tid == 0) counts[i] = 0;
    return;
  }
  __shared__ int cnt;
  __shared__ int list[MAXC];
  if (tid == 0) cnt = 0;
  __syncthreads();

  const bool is_b32 = (mask32[0] == 1u);  // else 0x01010101 (byte mask)
  if (is_b32) {
    const uint4* m4 = (const uint4*)(mask32 + (size_t)i * S_LEN);
#pragma unroll
    for (int q = 0; q < 4; ++q) {
      uint4 v = m4[tid * 4 + q];
      int base = tid * 16 + q * 4;
      if (v.x) { int p = atomicAdd(&cnt, 1); if (p < MAXC) list[p] = base + 0; }
      if (v.y) { int p = atomicAdd(&cnt, 1); if (p < MAXC) list[p] = base + 1; }
      if (v.z) { int p = atomicAdd(&cnt, 1); if (p < MAXC) list[p] = base + 2; }
      if (v.w) { int p = atomicAdd(&cnt, 1); if (p < MAXC) list[p] = base + 3; }
    }
  } else {
    const uint8_t* mrow = (const uint8_t*)mask32 + (size_t)i * S_LEN;
    uint4 mv = ((const uint4*)mrow)[tid];
    uint32_t w[4] = {mv.x, mv.y, mv.z, mv.w};
#pragma unroll
    for (int q = 0; q < 4; ++q)
#pragma unroll
      for (int b = 0; b < 4; ++b) {
        if ((w[q] >> (8 * b)) & 0xffu) {
          int p = atomicAdd(&cnt, 1);
          if (p < MAXC) list[p] = tid * 16 + q * 4 + b;
        }
      }
  }
  __syncthreads();
  int n = cnt < MAXC ? cnt : MAXC;
  if (tid == 0) counts[i] = n;
  for (int t = tid; t < n; t += 256) cols[(size_t)i * MAXC + t] = list[t];
}

// ---------------------------------------------------------------------------
// Sparse attention v5.
// Round-11 diagnosis: TA/L1-transaction bound. v4's QK loads touched 64
// distinct 64B lines per instruction (~64 TA cy); the fix is lane remap so
// 4 consecutive lanes read the 4 float4 of ONE line. Instruction t covers
// 4 whole columns (1KB, 16 lines, 4 lanes/line coalesced): lane =
// (sub=l>>4 -> which col, seg=(l>>2)&3, dd=l&3); per-col dot reduced via
// shfl_xor(1,2,4,8) within the 16-lane group. PV already at TA floor.
// ---------------------------------------------------------------------------
__global__ __launch_bounds__(256, 8) void attn_sparse(
    const float* __restrict__ Q, const float* __restrict__ K,
    const float* __restrict__ V, const int* __restrict__ counts,
    const int* __restrict__ cols, float* __restrict__ AO) {
  // XCD-chunked bijective swizzle (gridDim.x = 8192, divisible by 8)
  int bid = blockIdx.x;
  int bid2 = (bid & 7) * (int)(gridDim.x >> 3) + (bid >> 3);
  int wid = threadIdx.x >> 6, lane = threadIdx.x & 63;
  int task = bid2 * 4 + wid;
  int i = task >> 3, h = task & 7;
  if (i == 0 || i == S_LEN - 1) return;

  __shared__ float q_lds[4][DH];
  __shared__ float sc[4][MAXC];
  __shared__ float ps[4][MAXC];
  __shared__ int   cs[4][MAXC];

  int n = counts[i];
  q_lds[wid][lane] = Q[(size_t)i * C_DIM + h * DH + lane];
  const int* cl = cols + (size_t)i * MAXC;
  cs[wid][lane] = (lane < n) ? cl[lane] : 0;
  if (lane < MAXC - 64) cs[wid][64 + lane] = (64 + lane < n) ? cl[64 + lane] : 0;
  asm volatile("s_waitcnt lgkmcnt(0)" ::: "memory");

  if (n < 1) {  // defensive; never true for interior rows
    AO[(size_t)i * C_DIM + h * DH + lane] = 0.f;
    return;
  }

  // --- QK: instruction t covers cols [4t, 4t+4). Lane (sub,seg,dd) reads
  //     K[col][seg*16+dd*4 .. +4): 16 lanes = one col's full 256B slice,
  //     4 lanes coalesce per 64B line -> ~16 TA cycles per instruction. ---
  const int sub = lane >> 4;          // which of 4 cols
  const int seg = (lane >> 2) & 3;    // 64B segment within head slice
  const int dd = lane & 3;            // float4 within segment
  const float4 qv = *(const float4*)(q_lds[wid] + seg * 16 + dd * 4);
  const int nchunk = (n + 3) >> 2;    // wave-uniform, <= 20
  for (int t = 0; t < nchunk; ++t) {
    const int ci = t * 4 + sub;
    const int col = cs[wid][ci];
    float4 kr = *(const float4*)(K + (size_t)col * C_DIM + h * DH + seg * 16 + dd * 4);
    float s = kr.x * qv.x + kr.y * qv.y + kr.z * qv.z + kr.w * qv.w;
    s += __shfl_xor(s, 1);
    s += __shfl_xor(s, 2);
    s += __shfl_xor(s, 4);
    s += __shfl_xor(s, 8);
    if ((lane & 15) == 0) sc[wid][ci] = s * 0.125f;
  }
  asm volatile("s_waitcnt lgkmcnt(0)" ::: "memory");

  // --- softmax over the n scores (pad slots masked to -inf) ---
  float s0 = (lane < n) ? sc[wid][lane] : -INFINITY;
  float s1 = (64 + lane < n) ? sc[wid][64 + lane] : -INFINITY;
  float mx = fmaxf(s0, s1);
#pragma unroll
  for (int off = 32; off; off >>= 1) mx = fmaxf(mx, __shfl_xor(mx, off));
  float p0 = __expf(s0 - mx);  // 0 for masked lanes
  float p1 = __expf(s1 - mx);
  float l = p0 + p1;
#pragma unroll
  for (int off = 32; off; off >>= 1) l += __shfl_xor(l, off);
  float rl = 1.0f / l;

  ps[wid][lane] = p0 * rl;                       // pad slots -> 0
  if (lane < MAXC - 64) ps[wid][64 + lane] = p1 * rl;
  asm volatile("s_waitcnt lgkmcnt(0)" ::: "memory");

  // --- PV: lane = d; coalesced scalar V loads, 8 independent per batch ---
  float acc = 0.f;
  const float* Vh = V + h * DH + lane;
  const int npad = (n + 7) & ~7;  // <= MAXC, pad entries {p=0, col=0}
  for (int j0 = 0; j0 < npad; j0 += 8) {
    float pj[8], vv[8];
#pragma unroll
    for (int u = 0; u < 8; ++u) {
      pj[u] = ps[wid][j0 + u];
      vv[u] = Vh[(size_t)cs[wid][j0 + u] * C_DIM];
    }
#pragma unroll
    for (int u = 0; u < 8; ++u) acc = fmaf(pj[u], vv[u], acc);
  }
  AO[(size_t)i * C_DIM + h * DH + lane] = acc;
}

// ---------------------------------------------------------------------------
// Dense rows (0, S-1): NSPLIT=64, one 64-col chunk per wave (verified r8)
// ---------------------------------------------------------------------------
__global__ __launch_bounds__(256) void attn_dense(const float* __restrict__ Q,
                                                  const float* __restrict__ K,
                                                  const float* __restrict__ V,
                                                  float* __restrict__ part) {
  int wid = threadIdx.x >> 6, lane = threadIdx.x & 63;
  int gid = blockIdx.x * 4 + wid;  // 0..1023
  int task = gid >> 6;             // 0..15
  int split = gid & 63;
  int i = (task >> 3) ? (S_LEN - 1) : 0;
  int h = task & 7;

  __shared__ float q_lds[4][DH];
  __shared__ float pd[4][64];
  q_lds[wid][lane] = Q[(size_t)i * C_DIM + h * DH + lane];
  asm volatile("s_waitcnt lgkmcnt(0)" ::: "memory");
  const float4* q4 = (const float4*)q_lds[wid];

  const int c = split * 64 + lane;
  const float4* kp = (const float4*)(K + (size_t)c * C_DIM + h * DH);
  float s = 0.f;
#pragma unroll
  for (int dd = 0; dd < 16; ++dd) {
    float4 kv = kp[dd], qv = q4[dd];
    s += qv.x * kv.x + qv.y * kv.y + qv.z * kv.z + qv.w * kv.w;
  }
  s *= 0.125f;
  float m = s;
#pragma unroll
  for (int off = 32; off; off >>= 1) m = fmaxf(m, __shfl_xor(m, off));
  float p = __expf(s - m);
  float l = p;
#pragma unroll
  for (int off = 32; off; off >>= 1) l += __shfl_xor(l, off);

  pd[wid][lane] = p;
  asm volatile("s_waitcnt lgkmcnt(0)" ::: "memory");

  float acc = 0.f;
  const float* Vb = V + (size_t)(split * 64) * C_DIM + h * DH + lane;
  for (int j0 = 0; j0 < 64; j0 += 8) {
    float pj[8], vv[8];
#pragma unroll
    for (int u = 0; u < 8; ++u) {
      pj[u] = pd[wid][j0 + u];
      vv[u] = Vb[(size_t)(j0 + u) * C_DIM];
    }
#pragma unroll
    for (int u = 0; u < 8; ++u) acc = fmaf(pj[u], vv[u], acc);
  }
  float* pt = part + (size_t)(task * NSPLIT + split) * 68;
  pt[lane] = acc;
  if (lane == 0) {
    pt[64] = m;
    pt[65] = l;
  }
}

__global__ __launch_bounds__(64) void attn_combine(const float* __restrict__ part,
                                                   float* __restrict__ AO) {
  int task = blockIdx.x;  // 0..15
  int lane = threadIdx.x;
  float m = -INFINITY;
  for (int sp = 0; sp < NSPLIT; ++sp)
    m = fmaxf(m, part[(size_t)(task * NSPLIT + sp) * 68 + 64]);
  float l = 0.f, acc = 0.f;
  for (int sp = 0; sp < NSPLIT; ++sp) {
    const float* pt = part + (size_t)(task * NSPLIT + sp) * 68;
    float w = __expf(pt[64] - m);
    l += w * pt[65];
    acc += w * pt[lane];
  }
  int i = (task >> 3) ? (S_LEN - 1) : 0;
  int h = task & 7;
  AO[(size_t)i * C_DIM + h * DH + lane] = acc / l;
}

// ---------------------------------------------------------------------------
extern "C" void kernel_launch(void* const* d_in, const int* in_sizes, int n_in,
                              void* d_out, int out_size, void* d_ws,
                              size_t ws_size, hipStream_t stream) {
  const float* x = (const float*)d_in[0];
  const uint32_t* mask = (const uint32_t*)d_in[1];
  const float* Wq = (const float*)d_in[2];
  const float* bq = (const float*)d_in[3];
  const float* Wk = (const float*)d_in[4];
  const float* bk = (const float*)d_in[5];
  const float* Wv = (const float*)d_in[6];
  const float* bv = (const float*)d_in[7];
  const float* Wo = (const float*)d_in[8];
  const float* bo = (const float*)d_in[9];
  float* out = (float*)d_out;

  const size_t NELT = (size_t)S_LEN * C_DIM;  // 2,097,152
  const size_t NW = (size_t)C_DIM * C_DIM;    // 262,144

  float* Q = (float*)d_ws;
  float* Kb = Q + NELT;
  float* Vb = Kb + NELT;
  float* AO = Vb + NELT;
  int* counts = (int*)(AO + NELT);
  int* colsl = counts + S_LEN;
  float* part = (float*)(colsl + (size_t)S_LEN * MAXC);
  unsigned short* xh = (unsigned short*)(part + (size_t)DENSE_TASKS * NSPLIT * 68);
  unsigned short* xl = xh + NELT;
  unsigned short* AOh = xl + NELT;
  unsigned short* AOl = AOh + NELT;
  unsigned short* W4h = AOl + NELT;  // 4 * NW (q,k,v,o)
  unsigned short* W4l = W4h + 4 * NW;

  scan_mask<<<S_LEN, 256, 0, stream>>>(mask, counts, colsl);

  split_bf16<<<(NELT / 4 + 255) / 256, 256, 0, stream>>>(x, xh, xl, NELT / 4);
  split_bf16_w4<<<dim3(NW / 4 / 256, 4), 256, 0, stream>>>(Wq, Wk, Wv, Wo, W4h, W4l);
  qkv_gemm_mfma<<<dim3(C_DIM / 64, S_LEN / 128, 3), 256, 0, stream>>>(
      xh, xl, W4h, W4l, bq, bk, bv, Q);

  attn_sparse<<<(S_LEN * H_NUM) / 4, 256, 0, stream>>>(Q, Kb, Vb, counts, colsl, AO);
  attn_dense<<<(DENSE_TASKS * NSPLIT) / 4, 256, 0, stream>>>(Q, Kb, Vb, part);
  attn_combine<<<DENSE_TASKS, 64, 0, stream>>>(part, AO);

  split_bf16<<<(NELT / 4 + 255) / 256, 256, 0, stream>>>(AO, AOh, AOl, NELT / 4);
  o_gemm_mfma<<<dim3(C_DIM / 64, S_LEN / 128, 1), 256, 0, stream>>>(
      AOh, AOl, W4h, W4l, bo, out);
}